// Round 4
// baseline (71.555 us; speedup 1.0000x reference)
//
#include <hip/hip_runtime.h>

typedef float v2f __attribute__((ext_vector_type(2)));

#if defined(__has_builtin) && __has_builtin(__builtin_amdgcn_exp2f)
#  define FAST_EXP2(x) __builtin_amdgcn_exp2f(x)
#else
#  define FAST_EXP2(x) exp2f(x)
#endif
#if defined(__has_builtin) && __has_builtin(__builtin_amdgcn_rsqf)
#  define FAST_RSQ(x) __builtin_amdgcn_rsqf(x)
#else
#  define FAST_RSQ(x) rsqrtf(x)
#endif

// out[b,p,0] =  sum_v tau_v * exp(-r2/sig^2) * rsqrt(r2) * (p1 - x_v)
// out[b,p,1] = -sum_v tau_v * exp(-r2/sig^2) * rsqrt(r2) * (p0 - y_v)
//
// Coordinate pre-scaling (a = sqrt(log2e)/|sig|): dy' = a*(p0-y),
// dx' = a*(p1-x), r2' = dy'^2+dx'^2 -> exp(-r2/sig^2)*rsqrt(r2)*dx =
// exp2(-r2')*rsqrt(r2')*dx' (a cancels); exp negation via src modifier.
//
// R8 theory (fits R0/R2/R3): inner loop is LDS-PIPE-bound. Each wave's
// per-vortex ds_read_b128 broadcast costs ~12 cyc of the CU's single LDS
// pipe; 16 waves/CU x 12 = 192 cyc/round > ~140 cyc VALU issue. R2's
// +72 VALU cyc/iter tipping it VALU-bound (+17%) and R3's occupancy
// neutrality both fit this; pure-VALU or trans-bound models don't.
// Fix: 8 points/thread -> one ds_read_b128 per vortex serves 8 points;
// per-point LDS demand halves, VALU/pt unchanged -> VALU becomes the
// binding pipe. 256 blocks x 1024 thr, wave = 512 pts, split-K x16.
__global__ __launch_bounds__(1024, 4)
void GaussianFalloffKernel_83434034692733_kernel(
    const float* __restrict__ vortex,   // (2, 512, 6)
    const float* __restrict__ points,   // (2, 65536, 2)
    float* __restrict__ out)            // (2, 65536, 2)
{
    constexpr int NV  = 512;
    constexpr int NQ  = 16;                // split-K pieces (= waves/block)
    constexpr int VQ  = NV / NQ;           // 32 vortices per wave
    constexpr int PTS = 512;               // points per block (64 lanes x 8)
    constexpr int BPB = 65536 / PTS;       // 128 blocks per batch

    __shared__ float4 sv[NV];              // {a, -a*y, -a*x, tau}, 8 KB
    __shared__ v2f    red[NQ][PTS];        // 64 KB cross-wave partials

    const int b    = blockIdx.x / BPB;
    const int base = (blockIdx.x % BPB) * PTS;
    const int tid  = threadIdx.x;
    const int q    = tid >> 6;             // wave index == vortex slice
    const int h    = tid & 63;             // lane

    // Stage: one vortex per thread (first 512 threads).
    if (tid < NV) {
        const float* __restrict__ p = vortex + ((size_t)b * NV + tid) * 6;
        const float y   = p[0];
        const float x   = p[1];
        const float tau = p[2];
        const float sig = p[3];
        const float a   = 1.2011224087864498f / fabsf(sig);  // sqrt(log2e)/|sig|
        sv[tid] = make_float4(a, -a * y, -a * x, tau);
    }
    __syncthreads();

    // Eight points per thread: base + h + 64*{0..7}, packed SoA.
    const float2* __restrict__ pp =
        (const float2*)points + (size_t)b * 65536 + base;
    const float2 p0 = pp[h];
    const float2 p1 = pp[h + 64];
    const float2 p2 = pp[h + 128];
    const float2 p3 = pp[h + 192];
    const float2 p4 = pp[h + 256];
    const float2 p5 = pp[h + 320];
    const float2 p6 = pp[h + 384];
    const float2 p7 = pp[h + 448];
    const v2f pyA = { p0.x, p1.x }, pxA = { p0.y, p1.y };
    const v2f pyB = { p2.x, p3.x }, pxB = { p2.y, p3.y };
    const v2f pyC = { p4.x, p5.x }, pxC = { p4.y, p5.y };
    const v2f pyD = { p6.x, p7.x }, pxD = { p6.y, p7.y };

    v2f acc0A = { 0.0f, 0.0f }, acc1A = { 0.0f, 0.0f };
    v2f acc0B = { 0.0f, 0.0f }, acc1B = { 0.0f, 0.0f };
    v2f acc0C = { 0.0f, 0.0f }, acc1C = { 0.0f, 0.0f };
    v2f acc0D = { 0.0f, 0.0f }, acc1D = { 0.0f, 0.0f };

    const float4* __restrict__ svq = sv + q * VQ;
    #pragma unroll 4
    for (int v = 0; v < VQ; ++v) {
        const float4 s = svq[v];              // wave-uniform LDS broadcast
        const v2f dyA = pyA * s.x + s.y;      // a*(p0 - y_v)   (pk_fma)
        const v2f dxA = pxA * s.x + s.z;      // a*(p1 - x_v)
        const v2f dyB = pyB * s.x + s.y;
        const v2f dxB = pxB * s.x + s.z;
        const v2f dyC = pyC * s.x + s.y;
        const v2f dxC = pxC * s.x + s.z;
        const v2f dyD = pyD * s.x + s.y;
        const v2f dxD = pxD * s.x + s.z;
        const v2f r2A = dyA * dyA + dxA * dxA;
        const v2f r2B = dyB * dyB + dxB * dxB;
        const v2f r2C = dyC * dyC + dxC * dxC;
        const v2f r2D = dyD * dyD + dxD * dxD;
        v2f eA, eB, eC, eD, riA, riB, riC, riD;
        eA.x  = FAST_EXP2(-r2A.x);  eA.y  = FAST_EXP2(-r2A.y);
        eB.x  = FAST_EXP2(-r2B.x);  eB.y  = FAST_EXP2(-r2B.y);
        eC.x  = FAST_EXP2(-r2C.x);  eC.y  = FAST_EXP2(-r2C.y);
        eD.x  = FAST_EXP2(-r2D.x);  eD.y  = FAST_EXP2(-r2D.y);
        riA.x = FAST_RSQ(r2A.x);    riA.y = FAST_RSQ(r2A.y);
        riB.x = FAST_RSQ(r2B.x);    riB.y = FAST_RSQ(r2B.y);
        riC.x = FAST_RSQ(r2C.x);    riC.y = FAST_RSQ(r2C.y);
        riD.x = FAST_RSQ(r2D.x);    riD.y = FAST_RSQ(r2D.y);
        const v2f fA = (eA * riA) * s.w;      // tau * exp * rsqrt (scaled)
        const v2f fB = (eB * riB) * s.w;
        const v2f fC = (eC * riC) * s.w;
        const v2f fD = (eD * riD) * s.w;
        acc0A += fA * dxA;  acc1A -= fA * dyA;
        acc0B += fB * dxB;  acc1B -= fB * dyB;
        acc0C += fC * dxC;  acc1C -= fC * dyC;
        acc0D += fD * dxD;  acc1D -= fD * dyD;
    }

    red[q][h]       = (v2f){ acc0A.x, acc1A.x };
    red[q][h + 64]  = (v2f){ acc0A.y, acc1A.y };
    red[q][h + 128] = (v2f){ acc0B.x, acc1B.x };
    red[q][h + 192] = (v2f){ acc0B.y, acc1B.y };
    red[q][h + 256] = (v2f){ acc0C.x, acc1C.x };
    red[q][h + 320] = (v2f){ acc0C.y, acc1C.y };
    red[q][h + 384] = (v2f){ acc0D.x, acc1D.x };
    red[q][h + 448] = (v2f){ acc0D.y, acc1D.y };
    __syncthreads();

    // 1024 threads reduce 512 points: thread t handles point t/2, comp t&1.
    {
        const int pt = tid >> 1;
        const int c  = tid & 1;
        float r = red[0][pt][c];
        #pragma unroll
        for (int i = 1; i < NQ; ++i) r += red[i][pt][c];
        out[((size_t)b * 65536 + base + pt) * 2 + c] = r;
    }
}

extern "C" void kernel_launch(void* const* d_in, const int* in_sizes, int n_in,
                              void* d_out, int out_size, void* d_ws, size_t ws_size,
                              hipStream_t stream) {
    const float* vortex = (const float*)d_in[0];  // (2, 512, 6)
    const float* points = (const float*)d_in[1];  // (2, 256, 256, 2)
    float* out = (float*)d_out;                   // (2, 256, 256, 2)

    const int blocks = 2 * (65536 / 512);  // 256 blocks x 1024 threads
    GaussianFalloffKernel_83434034692733_kernel<<<blocks, 1024, 0, stream>>>(
        vortex, points, out);
}